// Round 1
// baseline (205.630 us; speedup 1.0000x reference)
//
#include <hip/hip_runtime.h>
#include <cmath>

namespace {

constexpr int N = 32, T = 1024, C = 512, K = 64;
constexpr float EPS = 1e-12f;
constexpr int LS = 65;  // LDS row stride (floats); 65 = conflict-free for our access patterns

// ---------------------------------------------------------------------------
// Kernel 1: logits = x @ W^T + b, softmax over K, write a [NT, K]
// Block: 256 threads, computes a 64(rows=t) x 64(cols=k) tile. Grid: NT/64.
// ---------------------------------------------------------------------------
__global__ __launch_bounds__(256) void k_softmax(
    const float* __restrict__ x, const float* __restrict__ W,
    const float* __restrict__ b, float* __restrict__ a_out) {
  __shared__ float XsT[64 * LS];  // [c][r] transposed
  __shared__ float WsT[64 * LS];  // [c][k] transposed
  __shared__ float inv_s[64];

  const int tid = threadIdx.x;
  const int ty = tid >> 4;   // 0..15 -> row group (4 rows each)
  const int tx = tid & 15;   // 0..15 -> col group (4 cols each)
  const long r0 = (long)blockIdx.x * 64;

  float acc[4][4] = {};
  const float4 breg = reinterpret_cast<const float4*>(b)[tx];

  for (int c0 = 0; c0 < C; c0 += 64) {
    // stage X tile [64r x 64c] and W tile [64k x 64c], both transposed (c-major)
#pragma unroll
    for (int q = 0; q < 4; ++q) {
      const int f = tid + q * 256;
      const int rr = f >> 4;       // row (t or k)
      const int cq = f & 15;       // float4 col index
      const float4 xv =
          reinterpret_cast<const float4*>(x + (r0 + rr) * C + c0)[cq];
      XsT[(cq * 4 + 0) * LS + rr] = xv.x;
      XsT[(cq * 4 + 1) * LS + rr] = xv.y;
      XsT[(cq * 4 + 2) * LS + rr] = xv.z;
      XsT[(cq * 4 + 3) * LS + rr] = xv.w;
      const float4 wv =
          reinterpret_cast<const float4*>(W + (long)rr * C + c0)[cq];
      WsT[(cq * 4 + 0) * LS + rr] = wv.x;
      WsT[(cq * 4 + 1) * LS + rr] = wv.y;
      WsT[(cq * 4 + 2) * LS + rr] = wv.z;
      WsT[(cq * 4 + 3) * LS + rr] = wv.w;
    }
    __syncthreads();

    for (int cc = 0; cc < 64; ++cc) {
      float af[4], bf[4];
#pragma unroll
      for (int i = 0; i < 4; ++i) af[i] = XsT[cc * LS + ty * 4 + i];
#pragma unroll
      for (int j = 0; j < 4; ++j) bf[j] = WsT[cc * LS + tx * 4 + j];
#pragma unroll
      for (int i = 0; i < 4; ++i)
#pragma unroll
        for (int j = 0; j < 4; ++j) acc[i][j] = fmaf(af[i], bf[j], acc[i][j]);
    }
    __syncthreads();
  }

  // Epilogue: logits -> LDS (reuse XsT as L[64 rows][64 k], stride LS)
  const float* bp = reinterpret_cast<const float*>(&breg);
#pragma unroll
  for (int i = 0; i < 4; ++i)
#pragma unroll
    for (int j = 0; j < 4; ++j)
      XsT[(ty * 4 + i) * LS + tx * 4 + j] = acc[i][j] + bp[j];
  __syncthreads();

  // softmax over k per row; one thread per row (tid < 64)
  if (tid < 64) {
    float m = -1e30f;
#pragma unroll 8
    for (int k = 0; k < K; ++k) m = fmaxf(m, XsT[tid * LS + k]);
    float s = 0.f;
#pragma unroll 8
    for (int k = 0; k < K; ++k) {
      const float e = expf(XsT[tid * LS + k] - m);
      XsT[tid * LS + k] = e;
      s += e;
    }
    inv_s[tid] = 1.0f / s;
  }
  __syncthreads();

  // coalesced float4 write of a
#pragma unroll
  for (int q = 0; q < 4; ++q) {
    const int f = tid + q * 256;
    const int rr = f >> 4;
    const int cq = f & 15;
    const float inv = inv_s[rr];
    float4 v;
    v.x = XsT[rr * LS + cq * 4 + 0] * inv;
    v.y = XsT[rr * LS + cq * 4 + 1] * inv;
    v.z = XsT[rr * LS + cq * 4 + 2] * inv;
    v.w = XsT[rr * LS + cq * 4 + 3] * inv;
    reinterpret_cast<float4*>(a_out + (r0 + rr) * K)[cq] = v;
  }
}

// ---------------------------------------------------------------------------
// Kernel 2: vlad[n,k,c] = sum_t a[n,t,k]*x[n,t,c] - asum[n,k]*cent[k,c]
// plus per-(n,k) sum of squares (atomicAdd). Block = (n, c-chunk of 64).
// Grid: N*8 = 256 blocks.
// ---------------------------------------------------------------------------
__global__ __launch_bounds__(256) void k_vlad(
    const float* __restrict__ x, const float* __restrict__ a,
    const float* __restrict__ cent, float* __restrict__ vlad,
    float* __restrict__ sumsq) {
  __shared__ float As[64 * LS];  // [tt][k]
  __shared__ float Xs[64 * LS];  // [tt][c]
  __shared__ float asum_s[64];
  __shared__ float red[64 * 17];

  const int tid = threadIdx.x;
  const int ty = tid >> 4;  // k group
  const int tx = tid & 15;  // c group
  const int n = blockIdx.x >> 3;
  const int c0 = (blockIdx.x & 7) * 64;

  const float* xn = x + (long)n * T * C;
  const float* an = a + (long)n * T * K;

  float acc[4][4] = {};
  float asum_acc[4] = {};

  for (int t0 = 0; t0 < T; t0 += 64) {
#pragma unroll
    for (int q = 0; q < 4; ++q) {
      const int f = tid + q * 256;
      const int tt = f >> 4;
      const int cq = f & 15;
      const float4 av =
          reinterpret_cast<const float4*>(an + (long)(t0 + tt) * K)[cq];
      As[tt * LS + cq * 4 + 0] = av.x;
      As[tt * LS + cq * 4 + 1] = av.y;
      As[tt * LS + cq * 4 + 2] = av.z;
      As[tt * LS + cq * 4 + 3] = av.w;
      const float4 xv =
          reinterpret_cast<const float4*>(xn + (long)(t0 + tt) * C + c0)[cq];
      Xs[tt * LS + cq * 4 + 0] = xv.x;
      Xs[tt * LS + cq * 4 + 1] = xv.y;
      Xs[tt * LS + cq * 4 + 2] = xv.z;
      Xs[tt * LS + cq * 4 + 3] = xv.w;
    }
    __syncthreads();

    for (int tt = 0; tt < 64; ++tt) {
      float af[4], xf[4];
#pragma unroll
      for (int i = 0; i < 4; ++i) af[i] = As[tt * LS + ty * 4 + i];
#pragma unroll
      for (int j = 0; j < 4; ++j) xf[j] = Xs[tt * LS + tx * 4 + j];
#pragma unroll
      for (int i = 0; i < 4; ++i) {
        asum_acc[i] += af[i];  // redundant across tx; only tx==0 publishes
#pragma unroll
        for (int j = 0; j < 4; ++j) acc[i][j] = fmaf(af[i], xf[j], acc[i][j]);
      }
    }
    __syncthreads();
  }

  if (tx == 0) {
#pragma unroll
    for (int i = 0; i < 4; ++i) asum_s[ty * 4 + i] = asum_acc[i];
  }
  __syncthreads();

  // epilogue: subtract asum*centroid, write vlad, accumulate sumsq
#pragma unroll
  for (int i = 0; i < 4; ++i) {
    const int kg = ty * 4 + i;
    const float as = asum_s[kg];
    const float4 cv =
        reinterpret_cast<const float4*>(cent + (long)kg * C + c0)[tx];
    float4 v;
    v.x = acc[i][0] - as * cv.x;
    v.y = acc[i][1] - as * cv.y;
    v.z = acc[i][2] - as * cv.z;
    v.w = acc[i][3] - as * cv.w;
    reinterpret_cast<float4*>(vlad + (long)n * K * C + (long)kg * C + c0)[tx] = v;
    red[kg * 17 + tx] = v.x * v.x + v.y * v.y + v.z * v.z + v.w * v.w;
  }
  __syncthreads();

  if (tid < 64) {
    float s = 0.f;
#pragma unroll
    for (int q = 0; q < 16; ++q) s += red[tid * 17 + q];
    atomicAdd(&sumsq[n * K + tid], s);
  }
}

// ---------------------------------------------------------------------------
// Kernel 3: out = vlad / (max(||vlad_k||,eps) * max(||intra-normed||,eps))
// Grid: N*16 = 512 blocks, each scales 2048 elements of one n.
// ---------------------------------------------------------------------------
__global__ __launch_bounds__(256) void k_norm(
    const float* __restrict__ vlad, const float* __restrict__ sumsq,
    float* __restrict__ out) {
  __shared__ float denom[64];
  __shared__ float contrib[64];
  __shared__ float ginv;

  const int tid = threadIdx.x;
  const int n = blockIdx.x >> 4;
  const int chunk = blockIdx.x & 15;

  if (tid < 64) {
    const float ss = sumsq[n * K + tid];
    const float d = fmaxf(sqrtf(ss), EPS);
    denom[tid] = d;
    contrib[tid] = ss / (d * d);
  }
  __syncthreads();
  if (tid == 0) {
    float s = 0.f;
#pragma unroll
    for (int k = 0; k < K; ++k) s += contrib[k];
    ginv = 1.0f / fmaxf(sqrtf(s), EPS);
  }
  __syncthreads();

  const long base = (long)n * K * C + (long)chunk * 2048;
#pragma unroll
  for (int q = 0; q < 2; ++q) {
    const int f4 = tid + q * 256;          // float4 index within chunk
    const long off = chunk * 2048 + (long)f4 * 4;  // element offset within n
    const int k = (int)(off >> 9);         // /512
    float4 v = reinterpret_cast<const float4*>(vlad + (long)n * K * C + off)[0];
    const float sc = ginv / denom[k];
    v.x *= sc; v.y *= sc; v.z *= sc; v.w *= sc;
    reinterpret_cast<float4*>(out + (long)n * K * C + off)[0] = v;
  }
}

}  // namespace

extern "C" void kernel_launch(void* const* d_in, const int* in_sizes, int n_in,
                              void* d_out, int out_size, void* d_ws,
                              size_t ws_size, hipStream_t stream) {
  const float* x = reinterpret_cast<const float*>(d_in[0]);     // [N,T,C]
  const float* W = reinterpret_cast<const float*>(d_in[1]);     // [K,C]
  const float* b = reinterpret_cast<const float*>(d_in[2]);     // [K]
  const float* cent = reinterpret_cast<const float*>(d_in[3]);  // [K,C]
  float* out = reinterpret_cast<float*>(d_out);                 // [N, K*C]

  float* ws = reinterpret_cast<float*>(d_ws);
  float* a = ws;                       // N*T*K   = 2,097,152 floats
  float* vlad = ws + (long)N * T * K;  // N*K*C   = 1,048,576 floats
  float* sumsq = vlad + (long)N * K * C;  // N*K  = 2048 floats

  hipMemsetAsync(sumsq, 0, (size_t)N * K * sizeof(float), stream);

  k_softmax<<<(N * T) / 64, 256, 0, stream>>>(x, W, b, a);
  k_vlad<<<N * 8, 256, 0, stream>>>(x, a, cent, vlad, sumsq);
  k_norm<<<N * 16, 256, 0, stream>>>(vlad, sumsq, out);
}

// Round 2
// 171.111 us; speedup vs baseline: 1.2017x; 1.2017x over previous
//
#include <hip/hip_runtime.h>
#include <cmath>

namespace {

constexpr int N = 32, T = 1024, C = 512, K = 64;
constexpr float EPS = 1e-12f;

// ---------------------------------------------------------------------------
// k_wt: transpose W[K][C] -> WT[C][K] (one-time, 128 KB)
// Grid: C/64 = 8 blocks x 256 threads.
// ---------------------------------------------------------------------------
__global__ __launch_bounds__(256) void k_wt(const float* __restrict__ W,
                                            float* __restrict__ WT) {
  __shared__ float tile[64 * 65];
  const int tid = threadIdx.x;
  const int c0 = blockIdx.x * 64;
#pragma unroll
  for (int q = 0; q < 4; ++q) {
    const int f = tid + q * 256;
    const int rr = f >> 4;   // k row
    const int cq = f & 15;   // c float4
    const float4 wv = reinterpret_cast<const float4*>(W + (long)rr * C + c0)[cq];
    tile[(cq * 4 + 0) * 65 + rr] = wv.x;
    tile[(cq * 4 + 1) * 65 + rr] = wv.y;
    tile[(cq * 4 + 2) * 65 + rr] = wv.z;
    tile[(cq * 4 + 3) * 65 + rr] = wv.w;
  }
  __syncthreads();
#pragma unroll
  for (int q = 0; q < 4; ++q) {
    const int f = tid + q * 256;
    const int rr = f >> 4;   // c row (within tile)
    const int cq = f & 15;   // k float4
    float4 v;
    v.x = tile[rr * 65 + cq * 4 + 0];
    v.y = tile[rr * 65 + cq * 4 + 1];
    v.z = tile[rr * 65 + cq * 4 + 2];
    v.w = tile[rr * 65 + cq * 4 + 3];
    reinterpret_cast<float4*>(WT + (long)(c0 + rr) * K)[cq] = v;
  }
}

// ---------------------------------------------------------------------------
// k_softmax: logits = x @ WT + b, softmax over K, a -> global, asum atomics.
// Tile 64t x 64k, BK=64. Grid NT/64 = 512, 256 threads, micro 4x4.
// XsT [c][t] stride 66 (8B-aligned b64 reads, 4-way staging writes max).
// WsT [c][k] stride 68 (16B-aligned b128 reads, direct float4 staging).
// ---------------------------------------------------------------------------
constexpr int SX = 66, SW = 68;

__global__ __launch_bounds__(256) void k_softmax(
    const float* __restrict__ x, const float* __restrict__ WT,
    const float* __restrict__ b, float* __restrict__ a_out,
    float* __restrict__ asum) {
  __shared__ float XsT[64 * SX];
  __shared__ float WsT[64 * SW];

  const int tid = threadIdx.x;
  const int ty = tid >> 4;   // t group (x4)
  const int tx = tid & 15;   // k group (x4)
  const long r0 = (long)blockIdx.x * 64;
  const int n = blockIdx.x >> 4;  // 16 blocks per n

  float acc[4][4] = {};
  const float4 breg = reinterpret_cast<const float4*>(b)[tx];

  for (int c0 = 0; c0 < C; c0 += 64) {
#pragma unroll
    for (int q = 0; q < 4; ++q) {
      const int f = tid + q * 256;
      const int rr = f >> 4;   // t row / c row
      const int cq = f & 15;
      const float4 xv =
          reinterpret_cast<const float4*>(x + (r0 + rr) * C + c0)[cq];
      XsT[(cq * 4 + 0) * SX + rr] = xv.x;
      XsT[(cq * 4 + 1) * SX + rr] = xv.y;
      XsT[(cq * 4 + 2) * SX + rr] = xv.z;
      XsT[(cq * 4 + 3) * SX + rr] = xv.w;
      // WT rows are c, cols k: direct float4 copy
      const float4 wv =
          reinterpret_cast<const float4*>(WT + (long)(c0 + rr) * K)[cq];
      *reinterpret_cast<float4*>(&WsT[rr * SW + cq * 4]) = wv;
    }
    __syncthreads();

#pragma unroll 4
    for (int cc = 0; cc < 64; ++cc) {
      const float2 a01 = *reinterpret_cast<const float2*>(&XsT[cc * SX + ty * 4]);
      const float2 a23 = *reinterpret_cast<const float2*>(&XsT[cc * SX + ty * 4 + 2]);
      const float4 bfv = *reinterpret_cast<const float4*>(&WsT[cc * SW + tx * 4]);
      const float af[4] = {a01.x, a01.y, a23.x, a23.y};
      const float bf[4] = {bfv.x, bfv.y, bfv.z, bfv.w};
#pragma unroll
      for (int i = 0; i < 4; ++i)
#pragma unroll
        for (int j = 0; j < 4; ++j) acc[i][j] = fmaf(af[i], bf[j], acc[i][j]);
    }
    __syncthreads();
  }

  // bias
  const float* bp = reinterpret_cast<const float*>(&breg);
#pragma unroll
  for (int i = 0; i < 4; ++i)
#pragma unroll
    for (int j = 0; j < 4; ++j) acc[i][j] += bp[j];

  // softmax over k (16 tx lanes x 4 regs) -- register-only via shfl_xor
  float pk[4] = {};  // per-thread asum partial for k = tx*4+j
#pragma unroll
  for (int i = 0; i < 4; ++i) {
    float m = fmaxf(fmaxf(acc[i][0], acc[i][1]), fmaxf(acc[i][2], acc[i][3]));
#pragma unroll
    for (int s = 1; s < 16; s <<= 1) m = fmaxf(m, __shfl_xor(m, s, 64));
    float sum = 0.f;
#pragma unroll
    for (int j = 0; j < 4; ++j) {
      acc[i][j] = __expf(acc[i][j] - m);
      sum += acc[i][j];
    }
#pragma unroll
    for (int s = 1; s < 16; s <<= 1) sum += __shfl_xor(sum, s, 64);
    const float inv = 1.0f / sum;
    float4 v;
    v.x = acc[i][0] * inv; v.y = acc[i][1] * inv;
    v.z = acc[i][2] * inv; v.w = acc[i][3] * inv;
    pk[0] += v.x; pk[1] += v.y; pk[2] += v.z; pk[3] += v.w;
    reinterpret_cast<float4*>(a_out + (r0 + ty * 4 + i) * K)[tx] = v;
  }
  // reduce asum partials over the 4 ty-groups of this wave, then atomic
#pragma unroll
  for (int j = 0; j < 4; ++j) {
    pk[j] += __shfl_xor(pk[j], 16, 64);
    pk[j] += __shfl_xor(pk[j], 32, 64);
  }
  if ((tid & 63) < 16) {
#pragma unroll
    for (int j = 0; j < 4; ++j)
      atomicAdd(&asum[n * K + tx * 4 + j], pk[j]);
  }
}

// ---------------------------------------------------------------------------
// k_vlad: part[tc][n][k][c] = sum_{t in chunk} a[n,t,k]*x[n,t,c]
// Tile 64k x 64c, per-block t-range T/TS. Grid N*8*TS, 256 threads, micro 4x4.
// Both LDS tiles row-major stride 68, pure b128 reads.
// ---------------------------------------------------------------------------
constexpr int SV = 68;

__global__ __launch_bounds__(256) void k_vlad(
    const float* __restrict__ x, const float* __restrict__ a,
    float* __restrict__ part, int TS) {
  __shared__ float As[64 * SV];
  __shared__ float Xs[64 * SV];

  const int tid = threadIdx.x;
  const int ty = tid >> 4;  // k group
  const int tx = tid & 15;  // c group
  const int bi = blockIdx.x;
  const int cchunk = bi & 7;
  const int tmp = bi >> 3;
  const int tchunk = tmp % TS;
  const int n = tmp / TS;
  const int c0 = cchunk * 64;
  const int tlen = T / TS;
  const int tbase = tchunk * tlen;

  const float* xn = x + (long)n * T * C;
  const float* an = a + (long)n * T * K;

  float acc[4][4] = {};

  for (int t0 = tbase; t0 < tbase + tlen; t0 += 64) {
#pragma unroll
    for (int q = 0; q < 4; ++q) {
      const int f = tid + q * 256;
      const int tt = f >> 4;
      const int cq = f & 15;
      const float4 av =
          reinterpret_cast<const float4*>(an + (long)(t0 + tt) * K)[cq];
      *reinterpret_cast<float4*>(&As[tt * SV + cq * 4]) = av;
      const float4 xv =
          reinterpret_cast<const float4*>(xn + (long)(t0 + tt) * C + c0)[cq];
      *reinterpret_cast<float4*>(&Xs[tt * SV + cq * 4]) = xv;
    }
    __syncthreads();

#pragma unroll 4
    for (int tt = 0; tt < 64; ++tt) {
      const float4 afv = *reinterpret_cast<const float4*>(&As[tt * SV + ty * 4]);
      const float4 xfv = *reinterpret_cast<const float4*>(&Xs[tt * SV + tx * 4]);
      const float af[4] = {afv.x, afv.y, afv.z, afv.w};
      const float xf[4] = {xfv.x, xfv.y, xfv.z, xfv.w};
#pragma unroll
      for (int i = 0; i < 4; ++i)
#pragma unroll
        for (int j = 0; j < 4; ++j) acc[i][j] = fmaf(af[i], xf[j], acc[i][j]);
    }
    __syncthreads();
  }

#pragma unroll
  for (int i = 0; i < 4; ++i) {
    const int kg = ty * 4 + i;
    float4 v;
    v.x = acc[i][0]; v.y = acc[i][1]; v.z = acc[i][2]; v.w = acc[i][3];
    reinterpret_cast<float4*>(
        part + (((long)tchunk * N + n) * K + kg) * C + c0)[tx] = v;
  }
}

// ---------------------------------------------------------------------------
// k_reduce: vlad[n,k,:] = sum_p part[p][n][k][:] - asum[n,k]*cent[k,:]
// plus sumsq[n,k] (direct write). Grid N*K = 2048 blocks x 128 threads.
// ---------------------------------------------------------------------------
__global__ __launch_bounds__(128) void k_reduce(
    const float* __restrict__ part, const float* __restrict__ asum,
    const float* __restrict__ cent, float* __restrict__ vlad,
    float* __restrict__ sumsq, int TS) {
  __shared__ float r2[2];
  const int tid = threadIdx.x;
  const int n = blockIdx.x >> 6;
  const int k = blockIdx.x & 63;
  const int c = tid * 4;

  float4 v = {0.f, 0.f, 0.f, 0.f};
  for (int p = 0; p < TS; ++p) {
    const float4 pv = *reinterpret_cast<const float4*>(
        part + (((long)p * N + n) * K + k) * C + c);
    v.x += pv.x; v.y += pv.y; v.z += pv.z; v.w += pv.w;
  }
  const float as = asum[n * K + k];
  const float4 cv = *reinterpret_cast<const float4*>(cent + (long)k * C + c);
  v.x -= as * cv.x; v.y -= as * cv.y; v.z -= as * cv.z; v.w -= as * cv.w;
  *reinterpret_cast<float4*>(vlad + ((long)n * K + k) * C + c) = v;

  float ss = v.x * v.x + v.y * v.y + v.z * v.z + v.w * v.w;
#pragma unroll
  for (int s = 1; s < 64; s <<= 1) ss += __shfl_xor(ss, s, 64);
  if ((tid & 63) == 0) r2[tid >> 6] = ss;
  __syncthreads();
  if (tid == 0) sumsq[n * K + k] = r2[0] + r2[1];
}

// ---------------------------------------------------------------------------
// k_norm: out = vlad / (||vlad_k|| * ||intra-normed||). Grid N*16 x 256.
// ---------------------------------------------------------------------------
__global__ __launch_bounds__(256) void k_norm(
    const float* __restrict__ vlad, const float* __restrict__ sumsq,
    float* __restrict__ out) {
  __shared__ float denom[64];
  __shared__ float contrib[64];
  __shared__ float ginv;

  const int tid = threadIdx.x;
  const int n = blockIdx.x >> 4;
  const int chunk = blockIdx.x & 15;

  if (tid < 64) {
    const float ss = sumsq[n * K + tid];
    const float d = fmaxf(sqrtf(ss), EPS);
    denom[tid] = d;
    contrib[tid] = ss / (d * d);
  }
  __syncthreads();
  if (tid == 0) {
    float s = 0.f;
#pragma unroll
    for (int k = 0; k < K; ++k) s += contrib[k];
    ginv = 1.0f / fmaxf(sqrtf(s), EPS);
  }
  __syncthreads();

#pragma unroll
  for (int q = 0; q < 2; ++q) {
    const int f4 = tid + q * 256;
    const long off = chunk * 2048 + (long)f4 * 4;
    const int k = (int)(off >> 9);
    float4 v = *reinterpret_cast<const float4*>(vlad + (long)n * K * C + off);
    const float sc = ginv / denom[k];
    v.x *= sc; v.y *= sc; v.z *= sc; v.w *= sc;
    *reinterpret_cast<float4*>(out + (long)n * K * C + off) = v;
  }
}

}  // namespace

extern "C" void kernel_launch(void* const* d_in, const int* in_sizes, int n_in,
                              void* d_out, int out_size, void* d_ws,
                              size_t ws_size, hipStream_t stream) {
  const float* x = reinterpret_cast<const float*>(d_in[0]);     // [N,T,C]
  const float* W = reinterpret_cast<const float*>(d_in[1]);     // [K,C]
  const float* b = reinterpret_cast<const float*>(d_in[2]);     // [K]
  const float* cent = reinterpret_cast<const float*>(d_in[3]);  // [K,C]
  float* out = reinterpret_cast<float*>(d_out);                 // [N, K*C]

  float* ws = reinterpret_cast<float*>(d_ws);
  const size_t A_SZ = (size_t)N * T * K;    // 2M floats
  const size_t PART1 = (size_t)N * K * C;   // 1M floats
  const size_t FIXED = (size_t)C * K + 2u * N * K;

  int TS = 4;
  while (TS > 1 &&
         (A_SZ + (size_t)TS * PART1 + FIXED) * sizeof(float) > ws_size)
    TS >>= 1;

  float* a = ws;
  float* part = ws + A_SZ;
  float* wt = part + (size_t)TS * PART1;
  float* asum = wt + (size_t)C * K;
  float* sumsq = asum + (size_t)N * K;
  float* vlad = ws;  // aliases a (dead after k_vlad)

  hipMemsetAsync(asum, 0, (size_t)N * K * sizeof(float), stream);

  k_wt<<<C / 64, 256, 0, stream>>>(W, wt);
  k_softmax<<<(N * T) / 64, 256, 0, stream>>>(x, wt, b, a, asum);
  k_vlad<<<N * 8 * TS, 256, 0, stream>>>(x, a, part, TS);
  k_reduce<<<N * K, 128, 0, stream>>>(part, asum, cent, vlad, sumsq, TS);
  k_norm<<<N * 16, 256, 0, stream>>>(vlad, sumsq, out);
}

// Round 3
// 146.362 us; speedup vs baseline: 1.4049x; 1.1691x over previous
//
#include <hip/hip_runtime.h>
#include <cmath>

namespace {

constexpr int N = 32, T = 1024, C = 512, K = 64;
constexpr float EPS = 1e-12f;

typedef __attribute__((ext_vector_type(8))) short s8v;   // 8 x bf16 bits
typedef __attribute__((ext_vector_type(4))) short s4v;   // 4 x bf16 bits
typedef __attribute__((ext_vector_type(4))) float f4v;   // MFMA accumulator

__device__ inline unsigned short f2bh(float f) {
  __bf16 h = (__bf16)f;
  return __builtin_bit_cast(unsigned short, h);
}
__device__ inline float bh2f(unsigned short u) {
  __bf16 h = __builtin_bit_cast(__bf16, u);
  return (float)h;
}

#define MFMA16(A, B, Cc) __builtin_amdgcn_mfma_f32_16x16x32_bf16((A), (B), (Cc), 0, 0, 0)

// ---------------------------------------------------------------------------
// k_prep: split W[K][C] fp32 -> Wh, Wl bf16 (row-major [k][c], GEMM1 B layout)
// ---------------------------------------------------------------------------
__global__ __launch_bounds__(256) void k_prep(const float* __restrict__ W,
                                              unsigned short* __restrict__ Wh,
                                              unsigned short* __restrict__ Wl) {
  const int f = blockIdx.x * 256 + threadIdx.x;  // 0..8191, 4 elems each
  const float4 w = *(const float4*)&W[f * 4];
  float e[4] = {w.x, w.y, w.z, w.w};
  s4v h, l;
#pragma unroll
  for (int i = 0; i < 4; ++i) {
    unsigned short hb = f2bh(e[i]);
    h[i] = (short)hb;
    l[i] = (short)f2bh(e[i] - bh2f(hb));
  }
  *(s4v*)&Wh[f * 4] = h;
  *(s4v*)&Wl[f * 4] = l;
}

// ---------------------------------------------------------------------------
// k_gemm1: logits = x @ W^T + b (split-bf16 3-pass MFMA), softmax over K,
// writes a^T [n][k][t] as hi/lo bf16 + asum[n][k] fp32 (atomics).
// Grid NT/64 = 512 blocks x 512 threads (8 waves; wave = 16t x 32k quadrant).
// ---------------------------------------------------------------------------
__global__ __launch_bounds__(512, 4) void k_gemm1(
    const float* __restrict__ x, const unsigned short* __restrict__ Wh,
    const unsigned short* __restrict__ Wl, const float* __restrict__ b,
    unsigned short* __restrict__ ath, unsigned short* __restrict__ atl,
    float* __restrict__ asum) {
  __shared__ __align__(16) unsigned short sm[4 * 64 * 72];  // 36864 B
  __shared__ float asum_l[64];
  unsigned short* xh_s = sm;                // [64 t][72] bf16
  unsigned short* xl_s = sm + 64 * 72;
  unsigned short* wh_s = sm + 2 * 64 * 72;  // [64 k][72]
  unsigned short* wl_s = sm + 3 * 64 * 72;

  const int tid = threadIdx.x;
  const int w = tid >> 6, lane = tid & 63, lm = lane & 15, lq = lane >> 4;
  const int tt = w >> 1;  // t-tile (16 rows)
  const int kh = w & 1;   // k-half (32 cols)
  const long r0 = (long)blockIdx.x * 64;
  const int n = blockIdx.x >> 4;
  const int tl0 = (blockIdx.x & 15) * 64;

  if (tid < 64) asum_l[tid] = 0.f;

  f4v acc0 = {0.f, 0.f, 0.f, 0.f}, acc1 = {0.f, 0.f, 0.f, 0.f};
  const float bias0 = b[kh * 32 + lm], bias1 = b[kh * 32 + 16 + lm];

  for (int c0 = 0; c0 < C; c0 += 64) {
    // stage x fp32 -> hi/lo bf16 [t][c], 2 rounds
#pragma unroll
    for (int rr = 0; rr < 2; ++rr) {
      const int f = tid + rr * 512, t = f >> 4, cg = f & 15;
      const float4 xv = *(const float4*)&x[(r0 + t) * C + c0 + cg * 4];
      float e[4] = {xv.x, xv.y, xv.z, xv.w};
      s4v h, l;
#pragma unroll
      for (int i = 0; i < 4; ++i) {
        unsigned short hb = f2bh(e[i]);
        h[i] = (short)hb;
        l[i] = (short)f2bh(e[i] - bh2f(hb));
      }
      *(s4v*)&xh_s[t * 72 + cg * 4] = h;
      *(s4v*)&xl_s[t * 72 + cg * 4] = l;
    }
    // stage W hi/lo [k][c], 1 round each
    {
      const int k = tid >> 3, u = tid & 7;
      *(s8v*)&wh_s[k * 72 + u * 8] = *(const s8v*)&Wh[k * C + c0 + u * 8];
      *(s8v*)&wl_s[k * 72 + u * 8] = *(const s8v*)&Wl[k * C + c0 + u * 8];
    }
    __syncthreads();

#pragma unroll
    for (int ks = 0; ks < 2; ++ks) {
      const int col = ks * 32 + lq * 8;
      const s8v ah = *(const s8v*)&xh_s[(tt * 16 + lm) * 72 + col];
      const s8v al = *(const s8v*)&xl_s[(tt * 16 + lm) * 72 + col];
      const s8v bh0 = *(const s8v*)&wh_s[(kh * 32 + lm) * 72 + col];
      const s8v bh1 = *(const s8v*)&wh_s[(kh * 32 + 16 + lm) * 72 + col];
      const s8v bl0 = *(const s8v*)&wl_s[(kh * 32 + lm) * 72 + col];
      const s8v bl1 = *(const s8v*)&wl_s[(kh * 32 + 16 + lm) * 72 + col];
      acc0 = MFMA16(ah, bh0, acc0);
      acc0 = MFMA16(ah, bl0, acc0);
      acc0 = MFMA16(al, bh0, acc0);
      acc1 = MFMA16(ah, bh1, acc1);
      acc1 = MFMA16(ah, bl1, acc1);
      acc1 = MFMA16(al, bh1, acc1);
    }
    __syncthreads();
  }

  // dump logits + bias into LDS [64 t][68] fp32 (reuses sm)
  float* Ls = (float*)sm;                              // 17408 B
  unsigned short* ath_l = sm + 8704;                   // [64 k][76] bf16
  unsigned short* atl_l = sm + 8704 + 4864;
#pragma unroll
  for (int r = 0; r < 4; ++r) {
    Ls[(tt * 16 + lq * 4 + r) * 68 + kh * 32 + lm] = acc0[r] + bias0;
    Ls[(tt * 16 + lq * 4 + r) * 68 + kh * 32 + 16 + lm] = acc1[r] + bias1;
  }
  __syncthreads();

  // softmax: 8 threads per t-row (each owns 8 k), register + shfl
  {
    const int r = tid >> 3, j = tid & 7;
    const float4 v0 = *(const float4*)&Ls[r * 68 + j * 8];
    const float4 v1 = *(const float4*)&Ls[r * 68 + j * 8 + 4];
    float a[8] = {v0.x, v0.y, v0.z, v0.w, v1.x, v1.y, v1.z, v1.w};
    float m = a[0];
#pragma unroll
    for (int i = 1; i < 8; ++i) m = fmaxf(m, a[i]);
#pragma unroll
    for (int s = 1; s < 8; s <<= 1) m = fmaxf(m, __shfl_xor(m, s, 64));
    float sum = 0.f;
#pragma unroll
    for (int i = 0; i < 8; ++i) {
      a[i] = __expf(a[i] - m);
      sum += a[i];
    }
#pragma unroll
    for (int s = 1; s < 8; s <<= 1) sum += __shfl_xor(sum, s, 64);
    const float inv = 1.f / sum;
    float ps[8];
#pragma unroll
    for (int i = 0; i < 8; ++i) {
      a[i] *= inv;
      ps[i] = a[i];
    }
    // reduce asum over this wave's 8 t-rows
#pragma unroll
    for (int s = 8; s < 64; s <<= 1)
#pragma unroll
      for (int i = 0; i < 8; ++i) ps[i] += __shfl_xor(ps[i], s, 64);
    if ((tid & 56) == 0) {
#pragma unroll
      for (int i = 0; i < 8; ++i) atomicAdd(&asum_l[j * 8 + i], ps[i]);
    }
    // transposed hi/lo write into LDS a^T tiles [k][t]
#pragma unroll
    for (int i = 0; i < 8; ++i) {
      const unsigned short hb = f2bh(a[i]);
      ath_l[(j * 8 + i) * 76 + r] = hb;
      atl_l[(j * 8 + i) * 76 + r] = f2bh(a[i] - bh2f(hb));
    }
  }
  __syncthreads();

  if (tid < 64) atomicAdd(&asum[n * K + tid], asum_l[tid]);
  // coalesced a^T global write: [n][k][t], b64 units
#pragma unroll
  for (int m = 0; m < 4; ++m) {
    const int idx = tid + m * 512;
    const int sel = idx >> 10, rem = idx & 1023, k = rem >> 4, uu = rem & 15;
    const unsigned short* src = sel ? atl_l : ath_l;
    unsigned short* dst = sel ? atl : ath;
    *(s4v*)&dst[((long)n * K + k) * T + tl0 + uu * 4] =
        *(const s4v*)&src[k * 76 + uu * 4];
  }
}

// ---------------------------------------------------------------------------
// k_gemm2: part[p][n][k][c] = sum_{t in chunk} a[t][k] * x[t][c], split-bf16
// 3-pass MFMA. Grid N*TS*8 x 256 (4 waves; wave = 32k x 32c quadrant).
// A = a^T [k][t] (b128 staging); B = x^T [c][t] built during staging.
// ---------------------------------------------------------------------------
__global__ __launch_bounds__(256, 4) void k_gemm2(
    const float* __restrict__ x, const unsigned short* __restrict__ ath,
    const unsigned short* __restrict__ atl, float* __restrict__ part, int TS) {
  __shared__ __align__(16) unsigned short sm[4 * 64 * 72];
  unsigned short* ah_s = sm;                // a^T hi [64 k][72]
  unsigned short* al_s = sm + 4608;         // a^T lo
  unsigned short* xh_s = sm + 9216;         // x^T hi [64 c][72]
  unsigned short* xl_s = sm + 13824;        // x^T lo

  const int tid = threadIdx.x;
  const int w = tid >> 6, lane = tid & 63, lm = lane & 15, lq = lane >> 4;
  const int kh = w >> 1;  // k-half (32 rows)
  const int ch = w & 1;   // c-half (32 cols)
  const int bi = blockIdx.x;
  const int cchunk = bi & 7;
  const int tmp = bi >> 3;
  const int tchunk = tmp % TS, n = tmp / TS;
  const int c0 = cchunk * 64;
  const int tlen = T / TS;

  f4v acc[2][2] = {{{0.f, 0.f, 0.f, 0.f}, {0.f, 0.f, 0.f, 0.f}},
                   {{0.f, 0.f, 0.f, 0.f}, {0.f, 0.f, 0.f, 0.f}}};

  for (int t0 = tchunk * tlen; t0 < tchunk * tlen + tlen; t0 += 64) {
    // a^T staging: 4 rounds of b128
#pragma unroll
    for (int m = 0; m < 4; ++m) {
      const int idx = tid + m * 256;
      const int sel = idx >> 9, rem = idx & 511, k = rem >> 3, u = rem & 7;
      const unsigned short* src = sel ? atl : ath;
      unsigned short* dst = sel ? al_s : ah_s;
      *(s8v*)&dst[k * 72 + u * 8] =
          *(const s8v*)&src[((long)n * K + k) * T + t0 + u * 8];
    }
    // x^T staging: fp32 -> hi/lo, 4-t packed b64 transposed writes
    {
      const int cg = tid & 15, tq = tid >> 4, t4 = tq * 4;
      float e[4][4];
#pragma unroll
      for (int i = 0; i < 4; ++i) {
        const float4 v =
            *(const float4*)&x[((long)n * T + t0 + t4 + i) * C + c0 + cg * 4];
        e[i][0] = v.x; e[i][1] = v.y; e[i][2] = v.z; e[i][3] = v.w;
      }
#pragma unroll
      for (int cc = 0; cc < 4; ++cc) {
        s4v h, l;
#pragma unroll
        for (int i = 0; i < 4; ++i) {
          unsigned short hb = f2bh(e[i][cc]);
          h[i] = (short)hb;
          l[i] = (short)f2bh(e[i][cc] - bh2f(hb));
        }
        *(s4v*)&xh_s[(cg * 4 + cc) * 72 + t4] = h;
        *(s4v*)&xl_s[(cg * 4 + cc) * 72 + t4] = l;
      }
    }
    __syncthreads();

#pragma unroll
    for (int ks = 0; ks < 2; ++ks) {
      const int col = ks * 32 + lq * 8;
      const s8v ah0 = *(const s8v*)&ah_s[(kh * 32 + lm) * 72 + col];
      const s8v ah1 = *(const s8v*)&ah_s[(kh * 32 + 16 + lm) * 72 + col];
      const s8v al0 = *(const s8v*)&al_s[(kh * 32 + lm) * 72 + col];
      const s8v al1 = *(const s8v*)&al_s[(kh * 32 + 16 + lm) * 72 + col];
      const s8v bh0 = *(const s8v*)&xh_s[(ch * 32 + lm) * 72 + col];
      const s8v bh1 = *(const s8v*)&xh_s[(ch * 32 + 16 + lm) * 72 + col];
      const s8v bl0 = *(const s8v*)&xl_s[(ch * 32 + lm) * 72 + col];
      const s8v bl1 = *(const s8v*)&xl_s[(ch * 32 + 16 + lm) * 72 + col];
      acc[0][0] = MFMA16(ah0, bh0, acc[0][0]);
      acc[0][0] = MFMA16(ah0, bl0, acc[0][0]);
      acc[0][0] = MFMA16(al0, bh0, acc[0][0]);
      acc[0][1] = MFMA16(ah0, bh1, acc[0][1]);
      acc[0][1] = MFMA16(ah0, bl1, acc[0][1]);
      acc[0][1] = MFMA16(al0, bh1, acc[0][1]);
      acc[1][0] = MFMA16(ah1, bh0, acc[1][0]);
      acc[1][0] = MFMA16(ah1, bl0, acc[1][0]);
      acc[1][0] = MFMA16(al1, bh0, acc[1][0]);
      acc[1][1] = MFMA16(ah1, bh1, acc[1][1]);
      acc[1][1] = MFMA16(ah1, bl1, acc[1][1]);
      acc[1][1] = MFMA16(al1, bh1, acc[1][1]);
    }
    __syncthreads();
  }

  float* pbase = part + ((long)tchunk * N + n) * K * C;
#pragma unroll
  for (int mt = 0; mt < 2; ++mt)
#pragma unroll
    for (int nt = 0; nt < 2; ++nt)
#pragma unroll
      for (int r = 0; r < 4; ++r) {
        const int k = kh * 32 + mt * 16 + lq * 4 + r;
        const int c = c0 + ch * 32 + nt * 16 + lm;
        pbase[(long)k * C + c] = acc[mt][nt][r];
      }
}

// ---------------------------------------------------------------------------
// k_reduce: vlad[n,k,:] = sum_p part[p][n][k][:] - asum[n,k]*cent[k,:]
// plus sumsq[n,k]. Grid N*K = 2048 x 128.
// ---------------------------------------------------------------------------
__global__ __launch_bounds__(128) void k_reduce(
    const float* __restrict__ part, const float* __restrict__ asum,
    const float* __restrict__ cent, float* __restrict__ vlad,
    float* __restrict__ sumsq, int TS) {
  __shared__ float r2[2];
  const int tid = threadIdx.x;
  const int n = blockIdx.x >> 6;
  const int k = blockIdx.x & 63;
  const int c = tid * 4;

  float4 v = {0.f, 0.f, 0.f, 0.f};
  for (int p = 0; p < TS; ++p) {
    const float4 pv =
        *(const float4*)&part[(((long)p * N + n) * K + k) * C + c];
    v.x += pv.x; v.y += pv.y; v.z += pv.z; v.w += pv.w;
  }
  const float as = asum[n * K + k];
  const float4 cv = *(const float4*)&cent[(long)k * C + c];
  v.x -= as * cv.x; v.y -= as * cv.y; v.z -= as * cv.z; v.w -= as * cv.w;
  *(float4*)&vlad[((long)n * K + k) * C + c] = v;

  float ss = v.x * v.x + v.y * v.y + v.z * v.z + v.w * v.w;
#pragma unroll
  for (int s = 1; s < 64; s <<= 1) ss += __shfl_xor(ss, s, 64);
  if ((tid & 63) == 0) r2[tid >> 6] = ss;
  __syncthreads();
  if (tid == 0) sumsq[n * K + k] = r2[0] + r2[1];
}

// ---------------------------------------------------------------------------
// k_norm: out = vlad / (||vlad_k|| * ||intra-normed||). Grid N*16 x 256.
// ---------------------------------------------------------------------------
__global__ __launch_bounds__(256) void k_norm(
    const float* __restrict__ vlad, const float* __restrict__ sumsq,
    float* __restrict__ out) {
  __shared__ float denom[64];
  __shared__ float contrib[64];
  __shared__ float ginv;

  const int tid = threadIdx.x;
  const int n = blockIdx.x >> 4;
  const int chunk = blockIdx.x & 15;

  if (tid < 64) {
    const float ss = sumsq[n * K + tid];
    const float d = fmaxf(sqrtf(ss), EPS);
    denom[tid] = d;
    contrib[tid] = ss / (d * d);
  }
  __syncthreads();
  if (tid == 0) {
    float s = 0.f;
#pragma unroll
    for (int k = 0; k < K; ++k) s += contrib[k];
    ginv = 1.0f / fmaxf(sqrtf(s), EPS);
  }
  __syncthreads();

#pragma unroll
  for (int q = 0; q < 2; ++q) {
    const int f4 = tid + q * 256;
    const long off = chunk * 2048 + (long)f4 * 4;
    const int k = (int)(off >> 9);
    float4 v = *(const float4*)&vlad[(long)n * K * C + off];
    const float sc = ginv / denom[k];
    v.x *= sc; v.y *= sc; v.z *= sc; v.w *= sc;
    *(float4*)&out[(long)n * K * C + off] = v;
  }
}

}  // namespace

extern "C" void kernel_launch(void* const* d_in, const int* in_sizes, int n_in,
                              void* d_out, int out_size, void* d_ws,
                              size_t ws_size, hipStream_t stream) {
  const float* x = reinterpret_cast<const float*>(d_in[0]);     // [N,T,C]
  const float* W = reinterpret_cast<const float*>(d_in[1]);     // [K,C]
  const float* b = reinterpret_cast<const float*>(d_in[2]);     // [K]
  const float* cent = reinterpret_cast<const float*>(d_in[3]);  // [K,C]
  float* out = reinterpret_cast<float*>(d_out);                 // [N, K*C]

  const size_t AT_BYTES = (size_t)N * K * T * 2;   // 4 MiB per component
  const size_t PART1 = (size_t)N * K * C * 4;      // 4 MiB per t-chunk
  const size_t W_BYTES = (size_t)K * C * 2;        // 64 KiB per component
  const size_t TAIL = 2 * W_BYTES + 2 * 8192;

  int TS = 4;
  while (TS > 1 && 2 * AT_BYTES + (size_t)TS * PART1 + TAIL > ws_size) TS >>= 1;

  char* p = (char*)d_ws;
  unsigned short* ath = (unsigned short*)p;        p += AT_BYTES;
  unsigned short* atl = (unsigned short*)p;        p += AT_BYTES;
  float* part = (float*)p;                         p += (size_t)TS * PART1;
  unsigned short* Wh = (unsigned short*)p;         p += W_BYTES;
  unsigned short* Wl = (unsigned short*)p;         p += W_BYTES;
  float* asum = (float*)p;                         p += 8192;
  float* sumsq = (float*)p;
  float* vlad = (float*)ath;  // aliases a^T (dead after k_gemm2)

  hipMemsetAsync(asum, 0, (size_t)N * K * sizeof(float), stream);

  k_prep<<<32, 256, 0, stream>>>(W, Wh, Wl);
  k_gemm1<<<(N * T) / 64, 512, 0, stream>>>(x, Wh, Wl, b, ath, atl, asum);
  k_gemm2<<<N * TS * 8, 256, 0, stream>>>(x, ath, atl, part, TS);
  k_reduce<<<N * K, 128, 0, stream>>>(part, asum, cent, vlad, sumsq, TS);
  k_norm<<<N * 16, 256, 0, stream>>>(vlad, sumsq, out);
}

// Round 4
// 133.197 us; speedup vs baseline: 1.5438x; 1.0988x over previous
//
#include <hip/hip_runtime.h>
#include <cmath>

namespace {

constexpr int N = 32, T = 1024, C = 512, K = 64;
constexpr float EPS = 1e-12f;

typedef short s8v __attribute__((ext_vector_type(8)));   // 8 x bf16 bits
typedef short s4v __attribute__((ext_vector_type(4)));   // 4 x bf16 bits
typedef float f4v __attribute__((ext_vector_type(4)));   // MFMA accumulator

__device__ inline unsigned short f2bh(float f) {
  __bf16 h = (__bf16)f;
  return __builtin_bit_cast(unsigned short, h);
}
__device__ inline float bh2f(unsigned short u) {
  __bf16 h = __builtin_bit_cast(__bf16, u);
  return (float)h;
}

#define MFMA16(A, B, Cc) __builtin_amdgcn_mfma_f32_16x16x32_bf16((A), (B), (Cc), 0, 0, 0)

// ---------------------------------------------------------------------------
// k_gemm1: logits = x @ W^T + b (split-bf16 3-pass MFMA), softmax over K,
// writes a^T [n][k][t] fp32 + asum_part[block][64].
// Grid NT/64 = 512 blocks x 256 threads (4 waves; wave = 32t x 32k, 2x2 tiles).
// W converted fp32->hi/lo bf16 during staging (no prep kernel).
// Register prefetch of next c-chunk overlaps global latency with MFMA.
// ---------------------------------------------------------------------------
__global__ __launch_bounds__(256, 4) void k_gemm1(
    const float* __restrict__ x, const float* __restrict__ W,
    const float* __restrict__ b, float* __restrict__ aT,
    float* __restrict__ asum_part) {
  __shared__ __align__(16) unsigned short sm[4 * 64 * 72];  // 36864 B
  __shared__ float asum_l[256];
  unsigned short* xh_s = sm;                // [64 t][72] bf16
  unsigned short* xl_s = sm + 64 * 72;
  unsigned short* wh_s = sm + 2 * 64 * 72;  // [64 k][72]
  unsigned short* wl_s = sm + 3 * 64 * 72;

  const int tid = threadIdx.x;
  const int w = tid >> 6, lane = tid & 63, lm = lane & 15, lq = lane >> 4;
  const int th = w >> 1;  // t-half (32 rows)
  const int kh = w & 1;   // k-half (32 cols)
  const long r0 = (long)blockIdx.x * 64;
  const int n = blockIdx.x >> 4, tl = blockIdx.x & 15;

  f4v acc[2][2] = {};
  float4 px[4], pw[4];
#pragma unroll
  for (int r = 0; r < 4; ++r) {
    const int f = tid + r * 256, t = f >> 4, cg = f & 15;
    px[r] = *(const float4*)&x[(r0 + t) * C + cg * 4];
    pw[r] = *(const float4*)&W[(long)t * C + cg * 4];
  }

  for (int c0 = 0; c0 < C; c0 += 64) {
    __syncthreads();
#pragma unroll
    for (int r = 0; r < 4; ++r) {
      const int f = tid + r * 256, t = f >> 4, cg = f & 15;
      const float ex[4] = {px[r].x, px[r].y, px[r].z, px[r].w};
      const float ew[4] = {pw[r].x, pw[r].y, pw[r].z, pw[r].w};
      s4v xh, xl, wh, wl;
#pragma unroll
      for (int i = 0; i < 4; ++i) {
        unsigned short hb = f2bh(ex[i]);
        xh[i] = (short)hb; xl[i] = (short)f2bh(ex[i] - bh2f(hb));
        hb = f2bh(ew[i]);
        wh[i] = (short)hb; wl[i] = (short)f2bh(ew[i] - bh2f(hb));
      }
      *(s4v*)&xh_s[t * 72 + cg * 4] = xh;
      *(s4v*)&xl_s[t * 72 + cg * 4] = xl;
      *(s4v*)&wh_s[t * 72 + cg * 4] = wh;
      *(s4v*)&wl_s[t * 72 + cg * 4] = wl;
    }
    if (c0 + 64 < C) {  // prefetch next chunk; loads fly during MFMA below
#pragma unroll
      for (int r = 0; r < 4; ++r) {
        const int f = tid + r * 256, t = f >> 4, cg = f & 15;
        px[r] = *(const float4*)&x[(r0 + t) * C + c0 + 64 + cg * 4];
        pw[r] = *(const float4*)&W[(long)t * C + c0 + 64 + cg * 4];
      }
    }
    __syncthreads();

#pragma unroll
    for (int ks = 0; ks < 2; ++ks) {
      const int col = ks * 32 + lq * 8;
      s8v ah[2], al[2], bh[2], bl[2];
#pragma unroll
      for (int i = 0; i < 2; ++i) {
        ah[i] = *(const s8v*)&xh_s[(th * 32 + i * 16 + lm) * 72 + col];
        al[i] = *(const s8v*)&xl_s[(th * 32 + i * 16 + lm) * 72 + col];
        bh[i] = *(const s8v*)&wh_s[(kh * 32 + i * 16 + lm) * 72 + col];
        bl[i] = *(const s8v*)&wl_s[(kh * 32 + i * 16 + lm) * 72 + col];
      }
#pragma unroll
      for (int i = 0; i < 2; ++i)
#pragma unroll
        for (int j = 0; j < 2; ++j) {
          acc[i][j] = MFMA16(ah[i], bh[j], acc[i][j]);
          acc[i][j] = MFMA16(ah[i], bl[j], acc[i][j]);
          acc[i][j] = MFMA16(al[i], bh[j], acc[i][j]);
        }
    }
  }
  __syncthreads();

  // logits + bias -> LDS Ls[64 t][68] fp32 ; Ls2 = a^T staging [64 k][68]
  float* Ls = (float*)sm;            // 17408 B
  float* Ls2 = (float*)(sm + 8704);  // 17408 B
  const float bias[2] = {b[kh * 32 + lm], b[kh * 32 + 16 + lm]};
#pragma unroll
  for (int i = 0; i < 2; ++i)
#pragma unroll
    for (int j = 0; j < 2; ++j)
#pragma unroll
      for (int r = 0; r < 4; ++r)
        Ls[(th * 32 + i * 16 + lq * 4 + r) * 68 + kh * 32 + j * 16 + lm] =
            acc[i][j][r] + bias[j];
  __syncthreads();

  // softmax: 4 threads per t-row, 16 k each, register + shfl
  {
    const int row = tid >> 2, q = tid & 3;
    float av[16];
#pragma unroll
    for (int u = 0; u < 4; ++u)
      *(float4*)&av[u * 4] = *(const float4*)&Ls[row * 68 + q * 16 + u * 4];
    float m = av[0];
#pragma unroll
    for (int i = 1; i < 16; ++i) m = fmaxf(m, av[i]);
    m = fmaxf(m, __shfl_xor(m, 1, 64));
    m = fmaxf(m, __shfl_xor(m, 2, 64));
    float sum = 0.f;
#pragma unroll
    for (int i = 0; i < 16; ++i) {
      av[i] = __expf(av[i] - m);
      sum += av[i];
    }
    sum += __shfl_xor(sum, 1, 64);
    sum += __shfl_xor(sum, 2, 64);
    const float inv = 1.f / sum;
    float ps[16];
#pragma unroll
    for (int i = 0; i < 16; ++i) {
      av[i] *= inv;
      ps[i] = av[i];
      Ls2[(q * 16 + i) * 68 + row] = av[i];  // transposed a^T [k][t]
    }
    // asum partial: reduce over this wave's 16 rows (lane strides 4..32)
#pragma unroll
    for (int s = 4; s < 64; s <<= 1)
#pragma unroll
      for (int i = 0; i < 16; ++i) ps[i] += __shfl_xor(ps[i], s, 64);
    if (lane < 4) {
#pragma unroll
      for (int i = 0; i < 16; ++i) asum_l[w * 64 + q * 16 + i] = ps[i];
    }
  }
  __syncthreads();

  if (tid < 64) {
    asum_part[(n * 16 + tl) * 64 + tid] = asum_l[tid] + asum_l[64 + tid] +
                                          asum_l[128 + tid] + asum_l[192 + tid];
  }
  // coalesced a^T global write [n][k][t] fp32
#pragma unroll
  for (int r = 0; r < 4; ++r) {
    const int u = tid + r * 256, k = u >> 4, tg = u & 15;
    *(float4*)&aT[((long)n * K + k) * T + tl * 64 + tg * 4] =
        *(const float4*)&Ls2[k * 68 + tg * 4];
  }
}

// ---------------------------------------------------------------------------
// k_gemm2: part[p][n][k][c] = sum_{t in chunk} a[t][k]*x[t][c], split-bf16.
// Grid N*TS*4 x 256 (4 waves; wave = 32k x 64c, 2x4 tiles). Block: 64k x 128c.
// a^T read fp32 (converted in staging, reg-prefetched); x^T built in staging.
// ---------------------------------------------------------------------------
__global__ __launch_bounds__(256, 2) void k_gemm2(
    const float* __restrict__ x, const float* __restrict__ aT,
    float* __restrict__ part, int TS) {
  __shared__ __align__(16) unsigned short sm[(2 * 64 + 2 * 128) * 72];  // 55296B
  unsigned short* ah_s = sm;                    // [64 k][72]
  unsigned short* al_s = sm + 64 * 72;
  unsigned short* xh_s = sm + 2 * 64 * 72;      // [128 c][72]
  unsigned short* xl_s = sm + 2 * 64 * 72 + 128 * 72;

  const int tid = threadIdx.x;
  const int w = tid >> 6, lane = tid & 63, lm = lane & 15, lq = lane >> 4;
  const int kh = w >> 1;  // 32k half
  const int ch = w & 1;   // 64c half
  const int bi = blockIdx.x;
  const int cchunk = bi & 3;
  const int tmp = bi >> 2;
  const int tchunk = tmp % TS, n = tmp / TS;
  const int c0 = cchunk * 128;
  const int tlen = T / TS, tbase = tchunk * tlen;

  f4v acc[2][4] = {};
  float4 pa[4];
#pragma unroll
  for (int r = 0; r < 4; ++r) {
    const int u = tid + r * 256, k = u >> 4, tg = u & 15;
    pa[r] = *(const float4*)&aT[((long)n * K + k) * T + tbase + tg * 4];
  }

  for (int t0 = tbase; t0 < tbase + tlen; t0 += 64) {
    __syncthreads();
    // a^T: convert fp32 -> hi/lo, store
#pragma unroll
    for (int r = 0; r < 4; ++r) {
      const int u = tid + r * 256, k = u >> 4, tg = u & 15;
      const float e[4] = {pa[r].x, pa[r].y, pa[r].z, pa[r].w};
      s4v h, l;
#pragma unroll
      for (int i = 0; i < 4; ++i) {
        unsigned short hb = f2bh(e[i]);
        h[i] = (short)hb;
        l[i] = (short)f2bh(e[i] - bh2f(hb));
      }
      *(s4v*)&ah_s[k * 72 + tg * 4] = h;
      *(s4v*)&al_s[k * 72 + tg * 4] = l;
    }
    if (t0 + 64 < tbase + tlen) {  // prefetch next a^T tile
#pragma unroll
      for (int r = 0; r < 4; ++r) {
        const int u = tid + r * 256, k = u >> 4, tg = u & 15;
        pa[r] = *(const float4*)&aT[((long)n * K + k) * T + t0 + 64 + tg * 4];
      }
    }
    // x^T staging: fp32 -> hi/lo, 4-t packed b64 transposed writes, 2 rounds
#pragma unroll
    for (int r = 0; r < 2; ++r) {
      const int u = tid + r * 256, cg = u & 31, tq = u >> 5;
      float e[4][4];
#pragma unroll
      for (int i = 0; i < 4; ++i) {
        const float4 v =
            *(const float4*)&x[((long)n * T + t0 + tq * 4 + i) * C + c0 + cg * 4];
        e[i][0] = v.x; e[i][1] = v.y; e[i][2] = v.z; e[i][3] = v.w;
      }
#pragma unroll
      for (int cc = 0; cc < 4; ++cc) {
        s4v h, l;
#pragma unroll
        for (int i = 0; i < 4; ++i) {
          unsigned short hb = f2bh(e[i][cc]);
          h[i] = (short)hb;
          l[i] = (short)f2bh(e[i][cc] - bh2f(hb));
        }
        *(s4v*)&xh_s[(cg * 4 + cc) * 72 + tq * 4] = h;
        *(s4v*)&xl_s[(cg * 4 + cc) * 72 + tq * 4] = l;
      }
    }
    __syncthreads();

#pragma unroll
    for (int ks = 0; ks < 2; ++ks) {
      const int col = ks * 32 + lq * 8;
      s8v ah[2], al[2];
#pragma unroll
      for (int i = 0; i < 2; ++i) {
        ah[i] = *(const s8v*)&ah_s[(kh * 32 + i * 16 + lm) * 72 + col];
        al[i] = *(const s8v*)&al_s[(kh * 32 + i * 16 + lm) * 72 + col];
      }
#pragma unroll
      for (int j = 0; j < 4; ++j) {
        const s8v bh = *(const s8v*)&xh_s[(ch * 64 + j * 16 + lm) * 72 + col];
        const s8v bl = *(const s8v*)&xl_s[(ch * 64 + j * 16 + lm) * 72 + col];
#pragma unroll
        for (int i = 0; i < 2; ++i) {
          acc[i][j] = MFMA16(ah[i], bh, acc[i][j]);
          acc[i][j] = MFMA16(ah[i], bl, acc[i][j]);
          acc[i][j] = MFMA16(al[i], bh, acc[i][j]);
        }
      }
    }
  }

  float* pb = part + ((long)tchunk * N + n) * K * C;
#pragma unroll
  for (int i = 0; i < 2; ++i)
#pragma unroll
    for (int j = 0; j < 4; ++j)
#pragma unroll
      for (int r = 0; r < 4; ++r) {
        const int k = kh * 32 + i * 16 + lq * 4 + r;
        const int c = c0 + ch * 64 + j * 16 + lm;
        pb[(long)k * C + c] = acc[i][j][r];
      }
}

// ---------------------------------------------------------------------------
// k_reduce: vlad[n,k,:] = sum_p part - asum*cent ; sumsq. Grid N*K x 128.
// asum[n,k] summed from the 16 per-block partials (broadcast scalar loads).
// ---------------------------------------------------------------------------
__global__ __launch_bounds__(128) void k_reduce(
    const float* __restrict__ part, const float* __restrict__ asum_part,
    const float* __restrict__ cent, float* __restrict__ vlad,
    float* __restrict__ sumsq, int TS) {
  __shared__ float r2[2];
  const int tid = threadIdx.x;
  const int n = blockIdx.x >> 6;
  const int k = blockIdx.x & 63;
  const int c = tid * 4;

  float as = 0.f;
#pragma unroll
  for (int tl = 0; tl < 16; ++tl) as += asum_part[(n * 16 + tl) * 64 + k];

  float4 v = {0.f, 0.f, 0.f, 0.f};
  for (int p = 0; p < TS; ++p) {
    const float4 pv = *(const float4*)&part[(((long)p * N + n) * K + k) * C + c];
    v.x += pv.x; v.y += pv.y; v.z += pv.z; v.w += pv.w;
  }
  const float4 cv = *(const float4*)&cent[(long)k * C + c];
  v.x -= as * cv.x; v.y -= as * cv.y; v.z -= as * cv.z; v.w -= as * cv.w;
  *(float4*)&vlad[((long)n * K + k) * C + c] = v;

  float ss = v.x * v.x + v.y * v.y + v.z * v.z + v.w * v.w;
#pragma unroll
  for (int s = 1; s < 64; s <<= 1) ss += __shfl_xor(ss, s, 64);
  if ((tid & 63) == 0) r2[tid >> 6] = ss;
  __syncthreads();
  if (tid == 0) sumsq[n * K + k] = r2[0] + r2[1];
}

// ---------------------------------------------------------------------------
// k_norm: out = vlad / (||vlad_k|| * ||intra-normed||). Grid N*16 x 256.
// ---------------------------------------------------------------------------
__global__ __launch_bounds__(256) void k_norm(
    const float* __restrict__ vlad, const float* __restrict__ sumsq,
    float* __restrict__ out) {
  __shared__ float denom[64];
  __shared__ float contrib[64];
  __shared__ float ginv;

  const int tid = threadIdx.x;
  const int n = blockIdx.x >> 4;
  const int chunk = blockIdx.x & 15;

  if (tid < 64) {
    const float ss = sumsq[n * K + tid];
    const float d = fmaxf(sqrtf(ss), EPS);
    denom[tid] = d;
    contrib[tid] = ss / (d * d);
  }
  __syncthreads();
  if (tid == 0) {
    float s = 0.f;
#pragma unroll
    for (int k = 0; k < K; ++k) s += contrib[k];
    ginv = 1.0f / fmaxf(sqrtf(s), EPS);
  }
  __syncthreads();

#pragma unroll
  for (int q = 0; q < 2; ++q) {
    const int f4 = tid + q * 256;
    const long off = chunk * 2048 + (long)f4 * 4;
    const int k = (int)(off >> 9);
    float4 v = *(const float4*)&vlad[(long)n * K * C + off];
    const float sc = ginv / denom[k];
    v.x *= sc; v.y *= sc; v.z *= sc; v.w *= sc;
    *(float4*)&out[(long)n * K * C + off] = v;
  }
}

}  // namespace

extern "C" void kernel_launch(void* const* d_in, const int* in_sizes, int n_in,
                              void* d_out, int out_size, void* d_ws,
                              size_t ws_size, hipStream_t stream) {
  const float* x = reinterpret_cast<const float*>(d_in[0]);     // [N,T,C]
  const float* W = reinterpret_cast<const float*>(d_in[1]);     // [K,C]
  const float* b = reinterpret_cast<const float*>(d_in[2]);     // [K]
  const float* cent = reinterpret_cast<const float*>(d_in[3]);  // [K,C]
  float* out = reinterpret_cast<float*>(d_out);                 // [N, K*C]

  const size_t AT_BYTES = (size_t)N * K * T * 4;  // 8 MiB (a^T fp32)
  const size_t PART1 = (size_t)N * K * C * 4;     // 4 MiB per t-chunk
  const size_t TAIL = 512 * 64 * 4 + 8192;        // asum_part + sumsq

  int TS = 4;
  while (TS > 1 && AT_BYTES + (size_t)TS * PART1 + TAIL > ws_size) TS >>= 1;

  char* p = (char*)d_ws;
  float* aTg = (float*)p;                p += AT_BYTES;
  float* part = (float*)p;               p += (size_t)TS * PART1;
  float* asum_part = (float*)p;          p += 512 * 64 * 4;
  float* sumsq = (float*)p;
  float* vlad = aTg;  // aliases a^T (dead after k_gemm2)

  k_gemm1<<<(N * T) / 64, 256, 0, stream>>>(x, W, b, aTg, asum_part);
  k_gemm2<<<N * TS * 4, 256, 0, stream>>>(x, aTg, part, TS);
  k_reduce<<<N * K, 128, 0, stream>>>(part, asum_part, cent, vlad, sumsq, TS);
  k_norm<<<N * 16, 256, 0, stream>>>(vlad, sumsq, out);
}

// Round 5
// 128.708 us; speedup vs baseline: 1.5976x; 1.0349x over previous
//
#include <hip/hip_runtime.h>
#include <cmath>

namespace {

constexpr int N = 32, T = 1024, C = 512, K = 64;
constexpr float EPS = 1e-12f;

typedef short s8v __attribute__((ext_vector_type(8)));   // 8 x bf16 bits
typedef short s4v __attribute__((ext_vector_type(4)));   // 4 x bf16 bits
typedef float f4v __attribute__((ext_vector_type(4)));   // MFMA accumulator

__device__ inline unsigned short f2bh(float f) {
  __bf16 h = (__bf16)f;
  return __builtin_bit_cast(unsigned short, h);
}
__device__ inline float bh2f(unsigned short u) {
  __bf16 h = __builtin_bit_cast(__bf16, u);
  return (float)h;
}

#define MFMA16(A, B, Cc) __builtin_amdgcn_mfma_f32_16x16x32_bf16((A), (B), (Cc), 0, 0, 0)

// ---------------------------------------------------------------------------
// k_gemm1: logits = x @ W^T + b (split-bf16 3-pass MFMA), softmax over K,
// writes a^T [n][k][t] fp32 + asum_part[block][64].
// Grid NT/64 = 512 blocks x 256 threads (4 waves; wave = 32t x 32k, 2x2 tiles).
// ---------------------------------------------------------------------------
__global__ __launch_bounds__(256, 4) void k_gemm1(
    const float* __restrict__ x, const float* __restrict__ W,
    const float* __restrict__ b, float* __restrict__ aT,
    float* __restrict__ asum_part) {
  __shared__ __align__(16) unsigned short sm[4 * 64 * 72];  // 36864 B
  __shared__ float asum_l[256];
  unsigned short* xh_s = sm;                // [64 t][72] bf16
  unsigned short* xl_s = sm + 64 * 72;
  unsigned short* wh_s = sm + 2 * 64 * 72;  // [64 k][72]
  unsigned short* wl_s = sm + 3 * 64 * 72;

  const int tid = threadIdx.x;
  const int w = tid >> 6, lane = tid & 63, lm = lane & 15, lq = lane >> 4;
  const int th = w >> 1;  // t-half (32 rows)
  const int kh = w & 1;   // k-half (32 cols)
  const long r0 = (long)blockIdx.x * 64;
  const int n = blockIdx.x >> 4, tl = blockIdx.x & 15;

  f4v acc[2][2] = {};
  float4 px[4], pw[4];
#pragma unroll
  for (int r = 0; r < 4; ++r) {
    const int f = tid + r * 256, t = f >> 4, cg = f & 15;
    px[r] = *(const float4*)&x[(r0 + t) * C + cg * 4];
    pw[r] = *(const float4*)&W[(long)t * C + cg * 4];
  }

  for (int c0 = 0; c0 < C; c0 += 64) {
    __syncthreads();
#pragma unroll
    for (int r = 0; r < 4; ++r) {
      const int f = tid + r * 256, t = f >> 4, cg = f & 15;
      const float ex[4] = {px[r].x, px[r].y, px[r].z, px[r].w};
      const float ew[4] = {pw[r].x, pw[r].y, pw[r].z, pw[r].w};
      s4v xh, xl, wh, wl;
#pragma unroll
      for (int i = 0; i < 4; ++i) {
        unsigned short hb = f2bh(ex[i]);
        xh[i] = (short)hb; xl[i] = (short)f2bh(ex[i] - bh2f(hb));
        hb = f2bh(ew[i]);
        wh[i] = (short)hb; wl[i] = (short)f2bh(ew[i] - bh2f(hb));
      }
      *(s4v*)&xh_s[t * 72 + cg * 4] = xh;
      *(s4v*)&xl_s[t * 72 + cg * 4] = xl;
      *(s4v*)&wh_s[t * 72 + cg * 4] = wh;
      *(s4v*)&wl_s[t * 72 + cg * 4] = wl;
    }
    if (c0 + 64 < C) {  // prefetch next chunk
#pragma unroll
      for (int r = 0; r < 4; ++r) {
        const int f = tid + r * 256, t = f >> 4, cg = f & 15;
        px[r] = *(const float4*)&x[(r0 + t) * C + c0 + 64 + cg * 4];
        pw[r] = *(const float4*)&W[(long)t * C + c0 + 64 + cg * 4];
      }
    }
    __syncthreads();

#pragma unroll
    for (int ks = 0; ks < 2; ++ks) {
      const int col = ks * 32 + lq * 8;
      s8v ah[2], al[2], bh[2], bl[2];
#pragma unroll
      for (int i = 0; i < 2; ++i) {
        ah[i] = *(const s8v*)&xh_s[(th * 32 + i * 16 + lm) * 72 + col];
        al[i] = *(const s8v*)&xl_s[(th * 32 + i * 16 + lm) * 72 + col];
        bh[i] = *(const s8v*)&wh_s[(kh * 32 + i * 16 + lm) * 72 + col];
        bl[i] = *(const s8v*)&wl_s[(kh * 32 + i * 16 + lm) * 72 + col];
      }
#pragma unroll
      for (int i = 0; i < 2; ++i)
#pragma unroll
        for (int j = 0; j < 2; ++j) {
          acc[i][j] = MFMA16(ah[i], bh[j], acc[i][j]);
          acc[i][j] = MFMA16(ah[i], bl[j], acc[i][j]);
          acc[i][j] = MFMA16(al[i], bh[j], acc[i][j]);
        }
    }
  }
  __syncthreads();

  // logits + bias -> LDS Ls[64 t][68] fp32 ; Ls2 = a^T staging [64 k][68]
  float* Ls = (float*)sm;            // 17408 B
  float* Ls2 = (float*)(sm + 8704);  // 17408 B
  const float bias[2] = {b[kh * 32 + lm], b[kh * 32 + 16 + lm]};
#pragma unroll
  for (int i = 0; i < 2; ++i)
#pragma unroll
    for (int j = 0; j < 2; ++j)
#pragma unroll
      for (int r = 0; r < 4; ++r)
        Ls[(th * 32 + i * 16 + lq * 4 + r) * 68 + kh * 32 + j * 16 + lm] =
            acc[i][j][r] + bias[j];
  __syncthreads();

  // softmax: 4 threads per t-row, 16 k each, register + shfl
  {
    const int row = tid >> 2, q = tid & 3;
    float av[16];
#pragma unroll
    for (int u = 0; u < 4; ++u)
      *(float4*)&av[u * 4] = *(const float4*)&Ls[row * 68 + q * 16 + u * 4];
    float m = av[0];
#pragma unroll
    for (int i = 1; i < 16; ++i) m = fmaxf(m, av[i]);
    m = fmaxf(m, __shfl_xor(m, 1, 64));
    m = fmaxf(m, __shfl_xor(m, 2, 64));
    float sum = 0.f;
#pragma unroll
    for (int i = 0; i < 16; ++i) {
      av[i] = __expf(av[i] - m);
      sum += av[i];
    }
    sum += __shfl_xor(sum, 1, 64);
    sum += __shfl_xor(sum, 2, 64);
    const float inv = 1.f / sum;
    float ps[16];
#pragma unroll
    for (int i = 0; i < 16; ++i) {
      av[i] *= inv;
      ps[i] = av[i];
      Ls2[(q * 16 + i) * 68 + row] = av[i];  // transposed a^T [k][t]
    }
#pragma unroll
    for (int s = 4; s < 64; s <<= 1)
#pragma unroll
      for (int i = 0; i < 16; ++i) ps[i] += __shfl_xor(ps[i], s, 64);
    if (lane < 4) {
#pragma unroll
      for (int i = 0; i < 16; ++i) asum_l[w * 64 + q * 16 + i] = ps[i];
    }
  }
  __syncthreads();

  if (tid < 64) {
    asum_part[(n * 16 + tl) * 64 + tid] = asum_l[tid] + asum_l[64 + tid] +
                                          asum_l[128 + tid] + asum_l[192 + tid];
  }
#pragma unroll
  for (int r = 0; r < 4; ++r) {
    const int u = tid + r * 256, k = u >> 4, tg = u & 15;
    *(float4*)&aT[((long)n * K + k) * T + tl * 64 + tg * 4] =
        *(const float4*)&Ls2[k * 68 + tg * 4];
  }
}

// ---------------------------------------------------------------------------
// k_gemm2: vlad[n,k,c] = sum_t a[t,k]*x[t,c] - asum*cent, full T per block.
// Grid N*8 = 256 blocks (n, 64c) x 256 threads (4 waves; wave = 32k x 32c).
// Fused epilogue: centroid subtract, vlad write, sumsq partials (no atomics).
// ---------------------------------------------------------------------------
__global__ __launch_bounds__(256, 2) void k_gemm2(
    const float* __restrict__ x, const float* __restrict__ aT,
    const float* __restrict__ asum_part, const float* __restrict__ cent,
    float* __restrict__ vlad, float* __restrict__ ssq_part) {
  __shared__ __align__(16) unsigned short sm[4 * 64 * 72];  // 36864 B
  __shared__ float asum_l[64];
  __shared__ float ssq_l[128];
  unsigned short* ah_s = sm;                // a^T hi [64 k][72]
  unsigned short* al_s = sm + 64 * 72;
  unsigned short* xh_s = sm + 2 * 64 * 72;  // x^T hi [64 c][72]
  unsigned short* xl_s = sm + 3 * 64 * 72;

  const int tid = threadIdx.x;
  const int w = tid >> 6, lane = tid & 63, lm = lane & 15, lq = lane >> 4;
  const int kh = w >> 1;  // 32k half
  const int ch = w & 1;   // 32c half
  const int n = blockIdx.x >> 3, cb = blockIdx.x & 7;
  const int c0 = cb * 64;

  if (tid < 64) {
    float s = 0.f;
#pragma unroll
    for (int tl = 0; tl < 16; ++tl) s += asum_part[(n * 16 + tl) * 64 + tid];
    asum_l[tid] = s;
  }

  f4v acc[2][2] = {};
  float4 pa[4], px[4];
#pragma unroll
  for (int r = 0; r < 4; ++r) {
    const int u = tid + r * 256, k = u >> 4, tg = u & 15;
    pa[r] = *(const float4*)&aT[((long)n * K + k) * T + tg * 4];
  }
  {
    const int cg = tid & 15, tq = tid >> 4;
#pragma unroll
    for (int i = 0; i < 4; ++i)
      px[i] = *(const float4*)&x[((long)n * T + tq * 4 + i) * C + c0 + cg * 4];
  }

  for (int t0 = 0; t0 < T; t0 += 64) {
    __syncthreads();
    // a^T: fp32 -> hi/lo
#pragma unroll
    for (int r = 0; r < 4; ++r) {
      const int u = tid + r * 256, k = u >> 4, tg = u & 15;
      const float e[4] = {pa[r].x, pa[r].y, pa[r].z, pa[r].w};
      s4v h, l;
#pragma unroll
      for (int i = 0; i < 4; ++i) {
        unsigned short hb = f2bh(e[i]);
        h[i] = (short)hb;
        l[i] = (short)f2bh(e[i] - bh2f(hb));
      }
      *(s4v*)&ah_s[k * 72 + tg * 4] = h;
      *(s4v*)&al_s[k * 72 + tg * 4] = l;
    }
    // x^T: fp32 -> hi/lo, 4-t packed transposed writes
    {
      const int cg = tid & 15, tq = tid >> 4, t4 = tq * 4;
      float e[4][4];
#pragma unroll
      for (int i = 0; i < 4; ++i) {
        e[i][0] = px[i].x; e[i][1] = px[i].y;
        e[i][2] = px[i].z; e[i][3] = px[i].w;
      }
#pragma unroll
      for (int cc = 0; cc < 4; ++cc) {
        s4v h, l;
#pragma unroll
        for (int i = 0; i < 4; ++i) {
          unsigned short hb = f2bh(e[i][cc]);
          h[i] = (short)hb;
          l[i] = (short)f2bh(e[i][cc] - bh2f(hb));
        }
        *(s4v*)&xh_s[(cg * 4 + cc) * 72 + t4] = h;
        *(s4v*)&xl_s[(cg * 4 + cc) * 72 + t4] = l;
      }
    }
    if (t0 + 64 < T) {  // prefetch next t-tile
#pragma unroll
      for (int r = 0; r < 4; ++r) {
        const int u = tid + r * 256, k = u >> 4, tg = u & 15;
        pa[r] = *(const float4*)&aT[((long)n * K + k) * T + t0 + 64 + tg * 4];
      }
      const int cg = tid & 15, tq = tid >> 4;
#pragma unroll
      for (int i = 0; i < 4; ++i)
        px[i] = *(const float4*)&x[((long)n * T + t0 + 64 + tq * 4 + i) * C +
                                   c0 + cg * 4];
    }
    __syncthreads();

#pragma unroll
    for (int ks = 0; ks < 2; ++ks) {
      const int col = ks * 32 + lq * 8;
      s8v ah[2], al[2], bh[2], bl[2];
#pragma unroll
      for (int i = 0; i < 2; ++i) {
        ah[i] = *(const s8v*)&ah_s[(kh * 32 + i * 16 + lm) * 72 + col];
        al[i] = *(const s8v*)&al_s[(kh * 32 + i * 16 + lm) * 72 + col];
        bh[i] = *(const s8v*)&xh_s[(ch * 32 + i * 16 + lm) * 72 + col];
        bl[i] = *(const s8v*)&xl_s[(ch * 32 + i * 16 + lm) * 72 + col];
      }
#pragma unroll
      for (int i = 0; i < 2; ++i)
#pragma unroll
        for (int j = 0; j < 2; ++j) {
          acc[i][j] = MFMA16(ah[i], bh[j], acc[i][j]);
          acc[i][j] = MFMA16(ah[i], bl[j], acc[i][j]);
          acc[i][j] = MFMA16(al[i], bh[j], acc[i][j]);
        }
    }
  }

  // fused epilogue: subtract asum*cent, write vlad, sumsq partials
  float ssq[2][4];
#pragma unroll
  for (int i = 0; i < 2; ++i)
#pragma unroll
    for (int r = 0; r < 4; ++r) ssq[i][r] = 0.f;

#pragma unroll
  for (int i = 0; i < 2; ++i) {
#pragma unroll
    for (int r = 0; r < 4; ++r) {
      const int k = kh * 32 + i * 16 + lq * 4 + r;
      const float as = asum_l[k];
#pragma unroll
      for (int j = 0; j < 2; ++j) {
        const int c = c0 + ch * 32 + j * 16 + lm;
        const float v = acc[i][j][r] - as * cent[(long)k * C + c];
        vlad[((long)n * K + k) * C + c] = v;
        ssq[i][r] += v * v;
      }
    }
  }
#pragma unroll
  for (int i = 0; i < 2; ++i)
#pragma unroll
    for (int r = 0; r < 4; ++r) {
      float s = ssq[i][r];
      s += __shfl_xor(s, 1, 64);
      s += __shfl_xor(s, 2, 64);
      s += __shfl_xor(s, 4, 64);
      s += __shfl_xor(s, 8, 64);
      ssq[i][r] = s;
    }
  if (lm == 0) {
#pragma unroll
    for (int i = 0; i < 2; ++i)
#pragma unroll
      for (int r = 0; r < 4; ++r)
        ssq_l[(kh * 32 + i * 16 + lq * 4 + r) * 2 + ch] = ssq[i][r];
  }
  __syncthreads();
  if (tid < 64)
    ssq_part[(n * 8 + cb) * 64 + tid] = ssq_l[tid * 2] + ssq_l[tid * 2 + 1];
}

// ---------------------------------------------------------------------------
// k_norm: out = vlad / (||vlad_k|| * ||intra-normed||). Grid N*16 x 256.
// ---------------------------------------------------------------------------
__global__ __launch_bounds__(256) void k_norm(
    const float* __restrict__ vlad, const float* __restrict__ ssq_part,
    float* __restrict__ out) {
  __shared__ float denom[64];
  __shared__ float contrib[64];
  __shared__ float ginv;

  const int tid = threadIdx.x;
  const int n = blockIdx.x >> 4;
  const int chunk = blockIdx.x & 15;

  if (tid < 64) {
    float ss = 0.f;
#pragma unroll
    for (int cb = 0; cb < 8; ++cb) ss += ssq_part[(n * 8 + cb) * 64 + tid];
    const float d = fmaxf(sqrtf(ss), EPS);
    denom[tid] = d;
    contrib[tid] = ss / (d * d);
  }
  __syncthreads();
  if (tid == 0) {
    float s = 0.f;
#pragma unroll
    for (int k = 0; k < K; ++k) s += contrib[k];
    ginv = 1.0f / fmaxf(sqrtf(s), EPS);
  }
  __syncthreads();

#pragma unroll
  for (int q = 0; q < 2; ++q) {
    const int f4 = tid + q * 256;
    const long off = chunk * 2048 + (long)f4 * 4;
    const int k = (int)(off >> 9);
    float4 v = *(const float4*)&vlad[(long)n * K * C + off];
    const float sc = ginv / denom[k];
    v.x *= sc; v.y *= sc; v.z *= sc; v.w *= sc;
    *(float4*)&out[(long)n * K * C + off] = v;
  }
}

}  // namespace

extern "C" void kernel_launch(void* const* d_in, const int* in_sizes, int n_in,
                              void* d_out, int out_size, void* d_ws,
                              size_t ws_size, hipStream_t stream) {
  const float* x = reinterpret_cast<const float*>(d_in[0]);     // [N,T,C]
  const float* W = reinterpret_cast<const float*>(d_in[1]);     // [K,C]
  const float* b = reinterpret_cast<const float*>(d_in[2]);     // [K]
  const float* cent = reinterpret_cast<const float*>(d_in[3]);  // [K,C]
  float* out = reinterpret_cast<float*>(d_out);                 // [N, K*C]

  float* p = reinterpret_cast<float*>(d_ws);
  float* aTg = p;                 p += (size_t)N * K * T;  // 8 MiB
  float* vlad = p;                p += (size_t)N * K * C;  // 4 MiB
  float* asum_part = p;           p += (size_t)512 * 64;   // 128 KiB
  float* ssq_part = p;            // 64 KiB

  k_gemm1<<<(N * T) / 64, 256, 0, stream>>>(x, W, b, aTg, asum_part);
  k_gemm2<<<N * 8, 256, 0, stream>>>(x, aTg, asum_part, cent, vlad, ssq_part);
  k_norm<<<N * 16, 256, 0, stream>>>(vlad, ssq_part, out);
}